// Round 10
// baseline (907.218 us; speedup 1.0000x reference)
//
#include <hip/hip_runtime.h>

#define E_CNT 32768
#define V_CNT 98304
#define D_ 128
#define VOCAB_ 2000
#define ITERS_ 6

typedef unsigned short u16;
typedef _Float16 f16;
typedef __attribute__((ext_vector_type(8))) _Float16 f16x8;
typedef __attribute__((ext_vector_type(4))) float f32x4;

__device__ __forceinline__ f32x4 MFh(f16x8 a, f16x8 b, f32x4 c) {
    return __builtin_amdgcn_mfma_f32_16x16x32_f16(a, b, c, 0, 0, 0);
}
// fast sigmoid/tanh: v_exp + v_rcp, no precise-divide expansion
__device__ __forceinline__ float sigmoid_f(float x) {
    return __builtin_amdgcn_rcpf(1.0f + __expf(-x));
}
__device__ __forceinline__ float tanh_f(float x) {
    float ax = fabsf(x);
    float t = fmaf(-2.0f, __builtin_amdgcn_rcpf(__expf(2.0f * ax) + 1.0f), 1.0f);
    return copysignf(t, x);
}

__global__ void detect_mask_kernel(const unsigned int* __restrict__ m, int* __restrict__ flag) {
    int i = blockIdx.x * 256 + threadIdx.x;
    if (i < 4096 && m[i] > 1u) atomicOr(flag, 1);
}

// Pack weights into MFMA fragment order.
// WvF (fp16): [nt(32)][kk(16)][lane(64)][8]  j = nt*16+(l&15), k = kk*32+(l>>4)*8+r
// WeF (fp16): [p(3)][nt(32)][kk(8)][64][8]
// OwF (fp16 hi/lo): [nt(125)][kk(4)][64][8]
__global__ void prep_kernel(
    const float* __restrict__ Wih_v2e, const float* __restrict__ Whh_v2e,
    const float* __restrict__ bih_v2e, const float* __restrict__ bhh_v2e,
    const float* __restrict__ Wih_e2v, const float* __restrict__ Whh_e2v,
    const float* __restrict__ bih_e2v, const float* __restrict__ bhh_e2v,
    const float* __restrict__ out_w,
    f16* __restrict__ WvF, f16* __restrict__ WeF,
    f16* __restrict__ OwFh, f16* __restrict__ OwFl,
    float* __restrict__ bv, float* __restrict__ be)
{
    int idx = blockIdx.x * 256 + threadIdx.x;
    if (idx < 262144) {
        const int r = idx & 7, l = (idx >> 3) & 63, t = idx >> 9;
        const int kk = t & 15, nt = t >> 4;
        const int j = nt * 16 + (l & 15);
        const int k = kk * 32 + (l >> 4) * 8 + r;
        const float w = (k < 384) ? Wih_v2e[j * 384 + k] : Whh_v2e[j * 128 + (k - 384)];
        WvF[idx] = (f16)w;
        return;
    }
    idx -= 262144;
    if (idx < 393216) {
        const int r = idx & 7, l = (idx >> 3) & 63, t = idx >> 9;  // t < 768
        const int kk = t & 7, nt = (t >> 3) & 31, p = t >> 8;
        const int j = nt * 16 + (l & 15);
        const int k = kk * 32 + (l >> 4) * 8 + r;
        const float w = (k < 128) ? Wih_e2v[(p * 512 + j) * 128 + k]
                                  : Whh_e2v[(p * 512 + j) * 128 + (k - 128)];
        WeF[idx] = (f16)w;
        return;
    }
    idx -= 393216;
    if (idx < 256000) {
        const int r = idx & 7, l = (idx >> 3) & 63, t = idx >> 9;  // t < 500
        const int kk = t & 3, nt = t >> 2;
        const int j = nt * 16 + (l & 15);
        const int k = kk * 32 + (l >> 4) * 8 + r;
        const float w = out_w[j * 128 + k];
        const f16 h = (f16)w;
        OwFh[idx] = h;
        OwFl[idx] = (f16)(w - (float)h);
        return;
    }
    idx -= 256000;
    if (idx < 512) { bv[idx] = bih_v2e[idx] + bhh_v2e[idx]; return; }
    idx -= 512;
    if (idx < 1536) { be[idx] = bih_e2v[idx] + bhh_e2v[idx]; return; }
}

// Persistent fused kernel (iterations + projection): 512 thr / 8 waves / 64 edges.
// LDS state in MFMA FRAGMENT ORDER:
//   HV[mt(4)][kk(12)][lane(64)][8]  element (row,col) -> mt=row>>4, kk=col>>5,
//       lane=((col>>3)&3)*16+(row&15), e=col&7.  48 KB
//   HE[mt(4)][kk(4)][lane(64)][8]   16 KB  -> 64 KB total, 2 blocks/CU, VGPR cap 128.
// Every ds_read_b128 is lane-linear (addr = l*16 + imm): ZERO bank conflicts AND zero
// addressing VALU (round-8 XOR fixed conflicts but burned VALU; round-9 padding fixed
// VALU but re-conflicted 1.6e7; fragment order fixes both).
// Projection fused at the end: HV fragments ARE the proj B-operand; swapped MFMA
// (A=out_w) gives float4 logit stores; no hv round-trip, no barriers in proj loop.
__global__ __launch_bounds__(512)
void fused_kernel(
    const int* __restrict__ x_v,
    const float* __restrict__ emb,
    const float* __restrict__ eiw, const float* __restrict__ eib,
    const f16* __restrict__ WvF, const f16* __restrict__ WeF,
    const float* __restrict__ bv, const float* __restrict__ be,
    const void* __restrict__ mask, const int* __restrict__ flagp,
    float* __restrict__ cvG,
    const f16* __restrict__ OwFh, const f16* __restrict__ OwFl,
    const float* __restrict__ out_b, float* __restrict__ out)
{
    __shared__ f16 HV[24576];   // 48 KB, fragment order
    __shared__ f16 HE[8192];    // 16 KB, fragment order

    const int tid = threadIdx.x;
    const int c = tid >> 6, l = tid & 63;
    const int lr = l & 15, lk = l >> 4;
    const int e0 = blockIdx.x * 64;

    // ---- init h_v from embeddings (fp16x8 chunks into fragment slots)
    for (int i = tid; i < 64 * 48; i += 512) {
        const int row = i / 48, seg = i % 48;       // col0 = seg*8
        int id = x_v[(e0 + row) * 3 + (seg >> 4)];
        if (id < 0 || id > VOCAB_) id = VOCAB_;
        const float* s = emb + id * D_ + ((seg * 8) & 127);
        float4 a = *(const float4*)s, b = *(const float4*)(s + 4);
        f16x8 H;
        H[0] = (f16)a.x; H[1] = (f16)a.y; H[2] = (f16)a.z; H[3] = (f16)a.w;
        H[4] = (f16)b.x; H[5] = (f16)b.y; H[6] = (f16)b.z; H[7] = (f16)b.w;
        *(f16x8*)&HV[((row >> 4) * 12 + (seg >> 2)) * 512 + (seg & 3) * 128 + (row & 15) * 8] = H;
    }
    // ---- init h_e (same vector for every edge)
    for (int i = tid; i < 64 * 16; i += 512) {
        const int row = i / 16, seg = i % 16;
        f16x8 H;
        #pragma unroll
        for (int j = 0; j < 8; ++j) H[j] = (f16)(eiw[seg * 8 + j] + eib[seg * 8 + j]);
        *(f16x8*)&HE[((row >> 4) * 4 + (seg >> 2)) * 512 + (seg & 3) * 128 + (row & 15) * 8] = H;
    }

    // ---- per-lane constants
    const int isByte = *flagp;
    unsigned mbits[3];
    #pragma unroll
    for (int p = 0; p < 3; ++p) {
        unsigned mb = 0;
        #pragma unroll
        for (int mt = 0; mt < 4; ++mt)
            #pragma unroll
            for (int r = 0; r < 4; ++r) {
                const int v = (e0 + mt * 16 + lk * 4 + r) * 3 + p;
                const bool m = isByte ? (((const unsigned char*)mask)[v] != 0)
                                      : (((const int*)mask)[v] != 0);
                mb |= (unsigned)m << (mt * 4 + r);
            }
        mbits[p] = mb;
    }
    const int d = c * 16 + lr;
    // cell-write base (halfs): column coords are per-thread constants
    const int wBase = (c >> 1) * 512 + ((c & 1) * 2 + (lr >> 3)) * 128 + lk * 32 + (lr & 7);
    float ce[4][4];
    #pragma unroll
    for (int mt = 0; mt < 4; ++mt)
        #pragma unroll
        for (int r = 0; r < 4; ++r) ce[mt][r] = 0.0f;

    __syncthreads();

// g outer, mt inner: same-accumulator MFMA distance 4
#define GEMM_STEP(WF, FBASE)                                                  \
    { _Pragma("unroll")                                                       \
      for (int g = 0; g < 4; ++g) {                                           \
          f16x8 B = *(const f16x8*)((WF) + (FBASE));                          \
          _Pragma("unroll")                                                   \
          for (int mt = 0; mt < 4; ++mt) acc[mt][g] = MFh(Ah[mt], B, acc[mt][g]); \
      } }

    const f16* HVl = HV + l * 8;   // lane-linear bases: all reads are base + imm
    const f16* HEl = HE + l * 8;

    #pragma unroll 1
    for (int it = 0; it < ITERS_; ++it) {
        // ======== vertex -> edge ========
        {
            f32x4 acc[4][4];
            #pragma unroll
            for (int mt = 0; mt < 4; ++mt)
                #pragma unroll
                for (int g = 0; g < 4; ++g) acc[mt][g] = (f32x4)0.0f;

            #pragma unroll 1
            for (int kk = 0; kk < 12; ++kk) {
                f16x8 Ah[4];
                #pragma unroll
                for (int mt = 0; mt < 4; ++mt)
                    Ah[mt] = *(const f16x8*)(HVl + (mt * 12 + kk) * 512);
                GEMM_STEP(WvF, (((g * 8 + c) * 16 + kk) * 64 + l) * 8)
            }
            #pragma unroll 1
            for (int kk = 12; kk < 16; ++kk) {
                f16x8 Ah[4];
                #pragma unroll
                for (int mt = 0; mt < 4; ++mt)
                    Ah[mt] = *(const f16x8*)(HEl + (mt * 4 + (kk - 12)) * 512);
                GEMM_STEP(WvF, (((g * 8 + c) * 16 + kk) * 64 + l) * 8)
            }
            __syncthreads();   // all HE reads done before HE writes
            const float bvi = bv[d], bvf = bv[128 + d], bvg = bv[256 + d], bvo = bv[384 + d];
            #pragma unroll
            for (int mt = 0; mt < 4; ++mt)
                #pragma unroll
                for (int r = 0; r < 4; ++r) {
                    float gi = sigmoid_f(acc[mt][0][r] + bvi);
                    float gf = sigmoid_f(acc[mt][1][r] + bvf);
                    float gg = tanh_f(acc[mt][2][r] + bvg);
                    float go = sigmoid_f(acc[mt][3][r] + bvo);
                    float cn = gf * ce[mt][r] + gi * gg;
                    ce[mt][r] = cn;
                    HE[wBase + mt * 2048 + r * 8] = (f16)(go * tanh_f(cn));
                }
            __syncthreads();   // HE complete before e2v reads
        }
        // ======== edge -> vertex (3 position-specific LSTMs) ========
        #pragma unroll 1
        for (int p = 0; p < 3; ++p) {
            f32x4 acc[4][4];
            #pragma unroll
            for (int mt = 0; mt < 4; ++mt)
                #pragma unroll
                for (int g = 0; g < 4; ++g) acc[mt][g] = (f32x4)0.0f;

            #pragma unroll 1
            for (int kk = 0; kk < 4; ++kk) {
                f16x8 Ah[4];
                #pragma unroll
                for (int mt = 0; mt < 4; ++mt)
                    Ah[mt] = *(const f16x8*)(HEl + (mt * 4 + kk) * 512);
                GEMM_STEP(WeF, ((((p * 32) + (g * 8 + c)) * 8 + kk) * 64 + l) * 8)
            }
            #pragma unroll 1
            for (int kk = 4; kk < 8; ++kk) {
                f16x8 Ah[4];
                #pragma unroll
                for (int mt = 0; mt < 4; ++mt)
                    Ah[mt] = *(const f16x8*)(HVl + (mt * 12 + 4 * p + (kk - 4)) * 512);
                GEMM_STEP(WeF, ((((p * 32) + (g * 8 + c)) * 8 + kk) * 64 + l) * 8)
            }
            __syncthreads();   // all HV[p]/HE reads done before HV[p] writes
            const float bei = be[p * 512 + d], bef = be[p * 512 + 128 + d];
            const float beg = be[p * 512 + 256 + d], beo = be[p * 512 + 384 + d];
            #pragma unroll
            for (int mt = 0; mt < 4; ++mt)
                #pragma unroll
                for (int r = 0; r < 4; ++r) {
                    if ((mbits[p] >> (mt * 4 + r)) & 1u) {
                        float gi = sigmoid_f(acc[mt][0][r] + bei);
                        float gf = sigmoid_f(acc[mt][1][r] + bef);
                        float gg = tanh_f(acc[mt][2][r] + beg);
                        float go = sigmoid_f(acc[mt][3][r] + beo);
                        const int row = mt * 16 + lk * 4 + r;
                        const size_t co = ((size_t)(e0 + row) * 3 + p) * 128 + d;
                        float cvold = (it == 0) ? 0.0f : cvG[co];
                        float cn = gf * cvold + gi * gg;
                        cvG[co] = cn;
                        HV[wBase + mt * 6144 + p * 2048 + r * 8] = (f16)(go * tanh_f(cn));
                    }
                }
            // no barrier between cell(p) and GEMM(p+1): cell writes HV tiles 4p..4p+3,
            // GEMM(p+1) reads tiles 4(p+1).. and HE - disjoint
        }
        __syncthreads();       // HV writes complete before next v2e (or proj)
    }

    // ======== fused projection: logits = h_v @ out_w^T + out_b ========
    // wave c: mt = c>>1 (16 edges = 48 vertices... 16 edge-rows x 3 p), h = c&1 (nt half).
    // A (swapped) = OwF fragments (global, L2; 4 same-mt waves share via L1);
    // B = HV fragments, loaded ONCE: PA[p][kk] (48 VGPR). No barriers.
    {
        const int mt = c >> 1, h = c & 1;
        f16x8 PA[3][4];
        #pragma unroll
        for (int p = 0; p < 3; ++p)
            #pragma unroll
            for (int kk = 0; kk < 4; ++kk)
                PA[p][kk] = *(const f16x8*)(HVl + (mt * 12 + 4 * p + kk) * 512);

        const int ntBeg = h ? 63 : 0;
        const int ntEnd = h ? 125 : 63;
        const size_t vrow = (size_t)(e0 + mt * 16 + lr) * 3;

        #pragma unroll 1
        for (int nt = ntBeg; nt < ntEnd; ++nt) {
            f16x8 Wh[4], Wl[4];
            #pragma unroll
            for (int kk = 0; kk < 4; ++kk) {
                const int fb = ((nt * 4 + kk) * 64 + l) * 8;
                Wh[kk] = *(const f16x8*)(OwFh + fb);
                Wl[kk] = *(const f16x8*)(OwFl + fb);
            }
            f32x4 acc[3];
            #pragma unroll
            for (int p = 0; p < 3; ++p) acc[p] = (f32x4)0.0f;
            #pragma unroll
            for (int kk = 0; kk < 4; ++kk)
                #pragma unroll
                for (int p = 0; p < 3; ++p) acc[p] = MFh(Wh[kk], PA[p][kk], acc[p]);
            #pragma unroll
            for (int kk = 0; kk < 4; ++kk)
                #pragma unroll
                for (int p = 0; p < 3; ++p) acc[p] = MFh(Wl[kk], PA[p][kk], acc[p]);

            const int n0 = nt * 16 + lk * 4;
            const float4 bb = *(const float4*)&out_b[n0];
            #pragma unroll
            for (int p = 0; p < 3; ++p) {
                float4 o = make_float4(acc[p][0] + bb.x, acc[p][1] + bb.y,
                                       acc[p][2] + bb.z, acc[p][3] + bb.w);
                *(float4*)&out[(vrow + p) * VOCAB_ + n0] = o;
            }
        }
    }
#undef GEMM_STEP
}

extern "C" void kernel_launch(void* const* d_in, const int* in_sizes, int n_in,
                              void* d_out, int out_size, void* d_ws, size_t ws_size,
                              hipStream_t stream)
{
    const int*   x_v     = (const int*)  d_in[0];
    const void*  mask    = d_in[1];
    const float* emb     = (const float*)d_in[2];
    const float* eiw     = (const float*)d_in[3];
    const float* eib     = (const float*)d_in[4];
    const float* Wih_v2e = (const float*)d_in[5];
    const float* Whh_v2e = (const float*)d_in[6];
    const float* bih_v2e = (const float*)d_in[7];
    const float* bhh_v2e = (const float*)d_in[8];
    const float* Wih_e2v = (const float*)d_in[9];
    const float* Whh_e2v = (const float*)d_in[10];
    const float* bih_e2v = (const float*)d_in[11];
    const float* bhh_e2v = (const float*)d_in[12];
    const float* out_w   = (const float*)d_in[13];
    const float* out_b   = (const float*)d_in[14];
    float* out = (float*)d_out;

    // d_ws carve (~52.7 MB)
    char* ws = (char*)d_ws;
    f16*   WvF  = (f16*)(ws);                  // 524288 B
    f16*   WeF  = (f16*)(ws + 524288);         // 786432
    f16*   OwFh = (f16*)(ws + 1310720);        // 512000
    f16*   OwFl = (f16*)(ws + 1822720);        // 512000
    float* bv   = (float*)(ws + 2334720);      // 2048
    float* be   = (float*)(ws + 2336768);      // 6144
    int*   flag = (int*)(ws + 2342912);        // 4
    float* cvG  = (float*)(ws + 2359296);      // 50331648  [E][3][128]

    hipMemsetAsync(flag, 0, 4, stream);
    detect_mask_kernel<<<16, 256, 0, stream>>>((const unsigned int*)mask, flag);
    prep_kernel<<<3568, 256, 0, stream>>>(Wih_v2e, Whh_v2e, bih_v2e, bhh_v2e,
                                          Wih_e2v, Whh_e2v, bih_e2v, bhh_e2v, out_w,
                                          WvF, WeF, OwFh, OwFl, bv, be);
    fused_kernel<<<E_CNT / 64, 512, 0, stream>>>(x_v, emb, eiw, eib,
                                                 WvF, WeF, bv, be,
                                                 mask, flag, cvG,
                                                 OwFh, OwFl, out_b, out);
}

// Round 12
// 786.717 us; speedup vs baseline: 1.1532x; 1.1532x over previous
//
#include <hip/hip_runtime.h>

#define E_CNT 32768
#define V_CNT 98304
#define D_ 128
#define VOCAB_ 2000
#define ITERS_ 6

typedef unsigned short u16;
typedef _Float16 f16;
typedef __attribute__((ext_vector_type(8))) _Float16 f16x8;
typedef __attribute__((ext_vector_type(4))) float f32x4;

__device__ __forceinline__ f32x4 MFh(f16x8 a, f16x8 b, f32x4 c) {
    return __builtin_amdgcn_mfma_f32_16x16x32_f16(a, b, c, 0, 0, 0);
}
// fast sigmoid/tanh: v_exp + v_rcp, no precise-divide expansion
__device__ __forceinline__ float sigmoid_f(float x) {
    return __builtin_amdgcn_rcpf(1.0f + __expf(-x));
}
__device__ __forceinline__ float tanh_f(float x) {
    float ax = fabsf(x);
    float t = fmaf(-2.0f, __builtin_amdgcn_rcpf(__expf(2.0f * ax) + 1.0f), 1.0f);
    return copysignf(t, x);
}

__global__ void detect_mask_kernel(const unsigned int* __restrict__ m, int* __restrict__ flag) {
    int i = blockIdx.x * 256 + threadIdx.x;
    if (i < 4096 && m[i] > 1u) atomicOr(flag, 1);
}

// Pack weights into MFMA fragment order.
// WvF (fp16): [nt(32)][kk(16)][lane(64)][8]  j = nt*16+(l&15), k = kk*32+(l>>4)*8+r
// WeF (fp16): [p(3)][nt(32)][kk(8)][64][8]
// OwF (fp16 hi/lo): [nt(125)][kk(4)][64][8]
__global__ void prep_kernel(
    const float* __restrict__ Wih_v2e, const float* __restrict__ Whh_v2e,
    const float* __restrict__ bih_v2e, const float* __restrict__ bhh_v2e,
    const float* __restrict__ Wih_e2v, const float* __restrict__ Whh_e2v,
    const float* __restrict__ bih_e2v, const float* __restrict__ bhh_e2v,
    const float* __restrict__ out_w,
    f16* __restrict__ WvF, f16* __restrict__ WeF,
    f16* __restrict__ OwFh, f16* __restrict__ OwFl,
    float* __restrict__ bv, float* __restrict__ be)
{
    int idx = blockIdx.x * 256 + threadIdx.x;
    if (idx < 262144) {
        const int r = idx & 7, l = (idx >> 3) & 63, t = idx >> 9;
        const int kk = t & 15, nt = t >> 4;
        const int j = nt * 16 + (l & 15);
        const int k = kk * 32 + (l >> 4) * 8 + r;
        const float w = (k < 384) ? Wih_v2e[j * 384 + k] : Whh_v2e[j * 128 + (k - 384)];
        WvF[idx] = (f16)w;
        return;
    }
    idx -= 262144;
    if (idx < 393216) {
        const int r = idx & 7, l = (idx >> 3) & 63, t = idx >> 9;  // t < 768
        const int kk = t & 7, nt = (t >> 3) & 31, p = t >> 8;
        const int j = nt * 16 + (l & 15);
        const int k = kk * 32 + (l >> 4) * 8 + r;
        const float w = (k < 128) ? Wih_e2v[(p * 512 + j) * 128 + k]
                                  : Whh_e2v[(p * 512 + j) * 128 + (k - 128)];
        WeF[idx] = (f16)w;
        return;
    }
    idx -= 393216;
    if (idx < 256000) {
        const int r = idx & 7, l = (idx >> 3) & 63, t = idx >> 9;  // t < 500
        const int kk = t & 3, nt = t >> 2;
        const int j = nt * 16 + (l & 15);
        const int k = kk * 32 + (l >> 4) * 8 + r;
        const float w = out_w[j * 128 + k];
        const f16 h = (f16)w;
        OwFh[idx] = h;
        OwFl[idx] = (f16)(w - (float)h);
        return;
    }
    idx -= 256000;
    if (idx < 512) { bv[idx] = bih_v2e[idx] + bhh_v2e[idx]; return; }
    idx -= 512;
    if (idx < 1536) { be[idx] = bih_e2v[idx] + bhh_e2v[idx]; return; }
}

// Persistent iteration kernel: 512 thr / 8 waves / 64 edges / all 6 iterations.
// LDS state in MFMA fragment order (lane-linear ds_reads: 0 conflicts, 0 addr VALU).
//   HV[mt(4)][kk(12)][lane(64)][8]  48 KB ; HE[mt(4)][kk(4)][lane(64)][8]  16 KB.
// Static 64 KB -> 2 blocks/CU -> honest 128-VGPR budget (round-8 mechanism).
// Round 11: B-fragment REGISTER PREFETCH - kk+1's weight fragments are loaded
// while kk's MFMAs run (round-10 diagnosis: every kk exposed ~300cyc L2 latency;
// MfmaUtil 16%, all pipes idle -> latency-bound, not resource-bound).
__global__ __launch_bounds__(512)
void fused_kernel(
    const int* __restrict__ x_v,
    const float* __restrict__ emb,
    const float* __restrict__ eiw, const float* __restrict__ eib,
    const f16* __restrict__ WvF, const f16* __restrict__ WeF,
    const float* __restrict__ bv, const float* __restrict__ be,
    const void* __restrict__ mask, const int* __restrict__ flagp,
    float* __restrict__ cvG,
    f16* __restrict__ hvOut)
{
    __shared__ f16 HV[24576];   // 48 KB, fragment order
    __shared__ f16 HE[8192];    // 16 KB, fragment order

    const int tid = threadIdx.x;
    const int c = tid >> 6, l = tid & 63;
    const int lr = l & 15, lk = l >> 4;
    const int e0 = blockIdx.x * 64;

    // ---- init h_v from embeddings (fp16x8 chunks into fragment slots)
    for (int i = tid; i < 64 * 48; i += 512) {
        const int row = i / 48, seg = i % 48;       // col0 = seg*8
        int id = x_v[(e0 + row) * 3 + (seg >> 4)];
        if (id < 0 || id > VOCAB_) id = VOCAB_;
        const float* s = emb + id * D_ + ((seg * 8) & 127);
        float4 a = *(const float4*)s, b = *(const float4*)(s + 4);
        f16x8 H;
        H[0] = (f16)a.x; H[1] = (f16)a.y; H[2] = (f16)a.z; H[3] = (f16)a.w;
        H[4] = (f16)b.x; H[5] = (f16)b.y; H[6] = (f16)b.z; H[7] = (f16)b.w;
        *(f16x8*)&HV[((row >> 4) * 12 + (seg >> 2)) * 512 + (seg & 3) * 128 + (row & 15) * 8] = H;
    }
    // ---- init h_e (same vector for every edge)
    for (int i = tid; i < 64 * 16; i += 512) {
        const int row = i / 16, seg = i % 16;
        f16x8 H;
        #pragma unroll
        for (int j = 0; j < 8; ++j) H[j] = (f16)(eiw[seg * 8 + j] + eib[seg * 8 + j]);
        *(f16x8*)&HE[((row >> 4) * 4 + (seg >> 2)) * 512 + (seg & 3) * 128 + (row & 15) * 8] = H;
    }

    // ---- per-lane constants
    const int isByte = *flagp;
    unsigned mbits[3];
    #pragma unroll
    for (int p = 0; p < 3; ++p) {
        unsigned mb = 0;
        #pragma unroll
        for (int mt = 0; mt < 4; ++mt)
            #pragma unroll
            for (int r = 0; r < 4; ++r) {
                const int v = (e0 + mt * 16 + lk * 4 + r) * 3 + p;
                const bool m = isByte ? (((const unsigned char*)mask)[v] != 0)
                                      : (((const int*)mask)[v] != 0);
                mb |= (unsigned)m << (mt * 4 + r);
            }
        mbits[p] = mb;
    }
    const int d = c * 16 + lr;
    // cell-write base (halfs): column coords are per-thread constants
    const int wBase = (c >> 1) * 512 + ((c & 1) * 2 + (lr >> 3)) * 128 + lk * 32 + (lr & 7);
    float ce[4][4];
    #pragma unroll
    for (int mt = 0; mt < 4; ++mt)
        #pragma unroll
        for (int r = 0; r < 4; ++r) ce[mt][r] = 0.0f;

    __syncthreads();

    const f16* HVl = HV + l * 8;   // lane-linear bases: all reads are base + imm
    const f16* HEl = HE + l * 8;

    #pragma unroll 1
    for (int it = 0; it < ITERS_; ++it) {
        // ======== vertex -> edge ========
        {
            f32x4 acc[4][4];
            #pragma unroll
            for (int mt = 0; mt < 4; ++mt)
                #pragma unroll
                for (int g = 0; g < 4; ++g) acc[mt][g] = (f32x4)0.0f;

            f16x8 Bc[4];
            #pragma unroll
            for (int g = 0; g < 4; ++g)
                Bc[g] = *(const f16x8*)(WvF + (((g * 8 + c) * 16) * 64 + l) * 8);

            #pragma unroll 2
            for (int kk = 0; kk < 16; ++kk) {
                f16x8 Bn[4];
                if (kk < 15) {
                    #pragma unroll
                    for (int g = 0; g < 4; ++g)
                        Bn[g] = *(const f16x8*)(WvF + (((g * 8 + c) * 16 + kk + 1) * 64 + l) * 8);
                }
                f16x8 Ah[4];
                if (kk < 12) {
                    #pragma unroll
                    for (int mt = 0; mt < 4; ++mt)
                        Ah[mt] = *(const f16x8*)(HVl + (mt * 12 + kk) * 512);
                } else {
                    #pragma unroll
                    for (int mt = 0; mt < 4; ++mt)
                        Ah[mt] = *(const f16x8*)(HEl + (mt * 4 + (kk - 12)) * 512);
                }
                #pragma unroll
                for (int g = 0; g < 4; ++g)
                    #pragma unroll
                    for (int mt = 0; mt < 4; ++mt)
                        acc[mt][g] = MFh(Ah[mt], Bc[g], acc[mt][g]);
                #pragma unroll
                for (int g = 0; g < 4; ++g) Bc[g] = Bn[g];
            }
            __syncthreads();   // all HE reads done before HE writes
            const float bvi = bv[d], bvf = bv[128 + d], bvg = bv[256 + d], bvo = bv[384 + d];
            #pragma unroll
            for (int mt = 0; mt < 4; ++mt)
                #pragma unroll
                for (int r = 0; r < 4; ++r) {
                    float gi = sigmoid_f(acc[mt][0][r] + bvi);
                    float gf = sigmoid_f(acc[mt][1][r] + bvf);
                    float gg = tanh_f(acc[mt][2][r] + bvg);
                    float go = sigmoid_f(acc[mt][3][r] + bvo);
                    float cn = gf * ce[mt][r] + gi * gg;
                    ce[mt][r] = cn;
                    HE[wBase + mt * 2048 + r * 8] = (f16)(go * tanh_f(cn));
                }
            __syncthreads();   // HE complete before e2v reads
        }
        // ======== edge -> vertex (3 position-specific LSTMs) ========
        #pragma unroll 1
        for (int p = 0; p < 3; ++p) {
            f32x4 acc[4][4];
            #pragma unroll
            for (int mt = 0; mt < 4; ++mt)
                #pragma unroll
                for (int g = 0; g < 4; ++g) acc[mt][g] = (f32x4)0.0f;

            f16x8 Bc[4];
            #pragma unroll
            for (int g = 0; g < 4; ++g)
                Bc[g] = *(const f16x8*)(WeF + ((((p * 32) + (g * 8 + c)) * 8) * 64 + l) * 8);

            #pragma unroll 2
            for (int kk = 0; kk < 8; ++kk) {
                f16x8 Bn[4];
                if (kk < 7) {
                    #pragma unroll
                    for (int g = 0; g < 4; ++g)
                        Bn[g] = *(const f16x8*)(WeF + ((((p * 32) + (g * 8 + c)) * 8 + kk + 1) * 64 + l) * 8);
                }
                f16x8 Ah[4];
                if (kk < 4) {
                    #pragma unroll
                    for (int mt = 0; mt < 4; ++mt)
                        Ah[mt] = *(const f16x8*)(HEl + (mt * 4 + kk) * 512);
                } else {
                    #pragma unroll
                    for (int mt = 0; mt < 4; ++mt)
                        Ah[mt] = *(const f16x8*)(HVl + (mt * 12 + 4 * p + (kk - 4)) * 512);
                }
                #pragma unroll
                for (int g = 0; g < 4; ++g)
                    #pragma unroll
                    for (int mt = 0; mt < 4; ++mt)
                        acc[mt][g] = MFh(Ah[mt], Bc[g], acc[mt][g]);
                #pragma unroll
                for (int g = 0; g < 4; ++g) Bc[g] = Bn[g];
            }
            __syncthreads();   // all HV[p]/HE reads done before HV[p] writes
            const float bei = be[p * 512 + d], bef = be[p * 512 + 128 + d];
            const float beg = be[p * 512 + 256 + d], beo = be[p * 512 + 384 + d];
            #pragma unroll
            for (int mt = 0; mt < 4; ++mt)
                #pragma unroll
                for (int r = 0; r < 4; ++r) {
                    if ((mbits[p] >> (mt * 4 + r)) & 1u) {
                        float gi = sigmoid_f(acc[mt][0][r] + bei);
                        float gf = sigmoid_f(acc[mt][1][r] + bef);
                        float gg = tanh_f(acc[mt][2][r] + beg);
                        float go = sigmoid_f(acc[mt][3][r] + beo);
                        const int row = mt * 16 + lk * 4 + r;
                        const size_t co = ((size_t)(e0 + row) * 3 + p) * 128 + d;
                        float cvold = (it == 0) ? 0.0f : cvG[co];
                        float cn = gf * cvold + gi * gg;
                        cvG[co] = cn;
                        HV[wBase + mt * 6144 + p * 2048 + r * 8] = (f16)(go * tanh_f(cn));
                    }
                }
            // no barrier between cell(p) and GEMM(p+1): cell writes HV tiles 4p..4p+3,
            // GEMM(p+1) reads tiles 4(p+1).. and HE - disjoint
        }
        __syncthreads();       // HV writes complete before next v2e (or copy-out)
    }

    // ---- write final h_v (fp16) for the projection kernel: [vertex][128] row-major
    for (int i = tid; i < 64 * 48; i += 512) {
        const int row = i / 48, seg = i % 48;
        *(f16x8*)&hvOut[(size_t)(e0 + row) * 384 + seg * 8] =
            *(const f16x8*)&HV[((row >> 4) * 12 + (seg >> 2)) * 512 + (seg & 3) * 128 + (row & 15) * 8];
    }
}

// logits = h_v @ out_w^T + out_b, swapped MFMA operands (A=out_w, B=h_v) -> each lane
// holds 4 consecutive vocab cols for one vertex -> float4 stores.
// 512 thr / 8 waves / 32 verts per wave / 384 blocks. NO barriers.
// Full register double-buffer of W fragments (8 f16x8 in flight for nt+1 while nt's
// MFMAs run) - round-10 diagnosis: serial load->MFMA per nt exposed ~300cyc L2 latency.
// 80KB static LDS pad pins occupancy to 2 blocks/CU -> honest 128-VGPR budget
// (round-6 bug: no-LDS kernels get allocator-targeted to 8 waves/EU = 64 VGPR = spills).
__global__ __launch_bounds__(512) void proj_kernel(
    const f16* __restrict__ hv,
    const f16* __restrict__ WFh, const f16* __restrict__ WFl,
    const float* __restrict__ out_b, float* __restrict__ out)
{
    __shared__ char occ_pad[81920];
    const int tid = threadIdx.x, l = tid & 63;
    occ_pad[tid] = (char)tid;
    __syncthreads();
    {
        int keep = (int)occ_pad[(tid + 1) & 511];
        asm volatile("" :: "v"(keep));   // keep the pad live (occupancy anchor)
    }

    const int wid = blockIdx.x * 8 + (tid >> 6);   // 0..3071
    const int v0 = wid * 32;
    const int lr = l & 15, lk = l >> 4;

    f16x8 Bv[2][4];
    #pragma unroll
    for (int vt = 0; vt < 2; ++vt)
        #pragma unroll
        for (int kk = 0; kk < 4; ++kk)
            Bv[vt][kk] = *(const f16x8*)(hv + (v0 + vt * 16 + lr) * D_ + kk * 32 + lk * 8);

    // current W fragments (hi 0..3, lo 4..7) for nt=0
    f16x8 Wc[8];
    #pragma unroll
    for (int kk = 0; kk < 4; ++kk) {
        Wc[kk]     = *(const f16x8*)(WFh + ((kk) * 64 + l) * 8);
        Wc[4 + kk] = *(const f16x8*)(WFl + ((kk) * 64 + l) * 8);
    }

    #pragma unroll 2
    for (int nt = 0; nt < 125; ++nt) {
        f16x8 Wn[8];
        if (nt < 124) {
            #pragma unroll
            for (int kk = 0; kk < 4; ++kk) {
                const int fb = (((nt + 1) * 4 + kk) * 64 + l) * 8;
                Wn[kk]     = *(const f16x8*)(WFh + fb);
                Wn[4 + kk] = *(const f16x8*)(WFl + fb);
            }
        }
        f32x4 t0 = (f32x4)0.0f, t1 = (f32x4)0.0f, u0 = (f32x4)0.0f, u1 = (f32x4)0.0f;
        #pragma unroll
        for (int kk = 0; kk < 4; ++kk) {
            t0 = MFh(Wc[kk], Bv[0][kk], t0);
            t1 = MFh(Wc[kk], Bv[1][kk], t1);
            u0 = MFh(Wc[4 + kk], Bv[0][kk], u0);
            u1 = MFh(Wc[4 + kk], Bv[1][kk], u1);
        }
        f32x4 a0 = t0 + u0;
        f32x4 a1 = t1 + u1;
        const int n0 = nt * 16 + lk * 4;
        const float4 bb = *(const float4*)&out_b[n0];
        {
            const size_t v = (size_t)(v0 + lr);
            float4 o = make_float4(a0[0] + bb.x, a0[1] + bb.y, a0[2] + bb.z, a0[3] + bb.w);
            *(float4*)&out[v * VOCAB_ + n0] = o;
        }
        {
            const size_t v = (size_t)(v0 + 16 + lr);
            float4 o = make_float4(a1[0] + bb.x, a1[1] + bb.y, a1[2] + bb.z, a1[3] + bb.w);
            *(float4*)&out[v * VOCAB_ + n0] = o;
        }
        #pragma unroll
        for (int q = 0; q < 8; ++q) Wc[q] = Wn[q];
    }
}

extern "C" void kernel_launch(void* const* d_in, const int* in_sizes, int n_in,
                              void* d_out, int out_size, void* d_ws, size_t ws_size,
                              hipStream_t stream)
{
    const int*   x_v     = (const int*)  d_in[0];
    const void*  mask    = d_in[1];
    const float* emb     = (const float*)d_in[2];
    const float* eiw     = (const float*)d_in[3];
    const float* eib     = (const float*)d_in[4];
    const float* Wih_v2e = (const float*)d_in[5];
    const float* Whh_v2e = (const float*)d_in[6];
    const float* bih_v2e = (const float*)d_in[7];
    const float* bhh_v2e = (const float*)d_in[8];
    const float* Wih_e2v = (const float*)d_in[9];
    const float* Whh_e2v = (const float*)d_in[10];
    const float* bih_e2v = (const float*)d_in[11];
    const float* bhh_e2v = (const float*)d_in[12];
    const float* out_w   = (const float*)d_in[13];
    const float* out_b   = (const float*)d_in[14];
    float* out = (float*)d_out;

    // d_ws carve (~78 MB)
    char* ws = (char*)d_ws;
    f16*   hv   = (f16*)(ws);                  // 25165824 B
    f16*   WvF  = (f16*)(ws + 25165824);       // 524288
    f16*   WeF  = (f16*)(ws + 25690112);       // 786432
    f16*   OwFh = (f16*)(ws + 26476544);       // 512000
    f16*   OwFl = (f16*)(ws + 26988544);       // 512000
    float* bv   = (float*)(ws + 27500544);     // 2048
    float* be   = (float*)(ws + 27502592);     // 6144
    int*   flag = (int*)(ws + 27508736);       // 4
    float* cvG  = (float*)(ws + 27525120);     // 50331648  [E][3][128]

    hipMemsetAsync(flag, 0, 4, stream);
    detect_mask_kernel<<<16, 256, 0, stream>>>((const unsigned int*)mask, flag);
    prep_kernel<<<3568, 256, 0, stream>>>(Wih_v2e, Whh_v2e, bih_v2e, bhh_v2e,
                                          Wih_e2v, Whh_e2v, bih_e2v, bhh_e2v, out_w,
                                          WvF, WeF, OwFh, OwFl, bv, be);
    fused_kernel<<<E_CNT / 64, 512, 0, stream>>>(x_v, emb, eiw, eib,
                                                 WvF, WeF, bv, be,
                                                 mask, flag, cvG, hv);
    proj_kernel<<<V_CNT / 256, 512, 0, stream>>>(hv, OwFh, OwFl, out_b, out);
}